// Round 9
// baseline (479.493 us; speedup 1.0000x reference)
//
#include <hip/hip_runtime.h>

// 2-layer LSTM, B=1024 T=512 D=1 H=64. 64 blocks x 1024 threads (16 waves).
// R9: NO per-step __syncthreads. Per-wave LDS flag dataflow sync:
//   waves 0-7  = layer0, wave wl owns unit-tiles {2wl, 2wl+1} (8 units)
//   waves 8-15 = layer1, same tiling.
// After writing its h-slice for step t, wave release-stores flag = t.
// L0 wave at t polls: min(flagL0) >= t-1 (RAW h0(t-1)) && min(flagL1) >= t-2
//   (WAR: h0(t) overwrites h0(t-2), read by L1 at step t-2).
// L1 wave at s polls: min(flagL0) >= s (RAW h0(s)) && min(flagL1) >= s-1
//   (RAW h1(s-1); also WAR for h1(s) over h1(s-2)).
// Deadlock-free: flags monotone; L1 lags L0 by <=0, L0 leads L1 by <=2.
// Operand-swapped MFMA (R8): A = pre-gathered W rows (4 units x 4 gates),
// B = h (k=unit, n=batch). D gives lane (c,quad) all 4 gates of
// (batch=c, unit=4*tile+quad) -> no shuffles, 2 points/lane.
// x(t) fetched via register prefetch (load t+1 during step t).

typedef _Float16 f16x8 __attribute__((ext_vector_type(8)));
typedef float f32x4 __attribute__((ext_vector_type(4)));

#define TSTEPS 512
#define MB 16
#define L2E 1.44269504088896340736f

__device__ __forceinline__ int hidx(int row, int j) {
    // swizzled index into a 16x64 half tile (16B-block XOR swizzle)
    return row * 64 + ((((j >> 3) ^ (row & 7)) << 3) | (j & 7));
}

__device__ __forceinline__ float lstm_point(float ai, float af, float ag, float ao,
                                            float& c) {
    // ai,af,ao pre-scaled by -log2e ; ag by +2log2e  (R2-R8 proven numerics)
    const float p  = __builtin_amdgcn_exp2f(ai);
    const float s_ = __builtin_amdgcn_exp2f(af);
    const float r_ = __builtin_amdgcn_exp2f(ag);
    const float v  = __builtin_amdgcn_exp2f(ao);
    const float f  = __builtin_amdgcn_rcpf(1.f + s_);
    const float ig = (r_ - 1.f) * __builtin_amdgcn_rcpf((1.f + p) * (1.f + r_));
    const float cc = __builtin_fmaf(f, c, ig);
    c = cc;
    const float w  = __builtin_amdgcn_exp2f(cc * (2.f * L2E));
    return (w - 1.f) * __builtin_amdgcn_rcpf((1.f + v) * (1.f + w));
}

__global__ __launch_bounds__(1024) void lstm2_kernel(
    const float* __restrict__ x,
    const float* __restrict__ W_ih0, const float* __restrict__ W_hh0,
    const float* __restrict__ b_ih0, const float* __restrict__ b_hh0,
    const float* __restrict__ W_ih1, const float* __restrict__ W_hh1,
    const float* __restrict__ b_ih1, const float* __restrict__ b_hh1,
    const float* __restrict__ W_fc,  const float* __restrict__ b_fc,
    float* __restrict__ out)
{
    __shared__ __align__(16) _Float16 h0s[2][16 * 64];
    __shared__ __align__(16) _Float16 h1s[2][16 * 64];
    __shared__ int flagL0[8];
    __shared__ int flagL1[8];

    const int tid  = (int)threadIdx.x;
    const int lane = tid & 63;
    const int w16  = tid >> 6;          // wave 0..15
    const bool gB  = (w16 >= 8);        // waves 8-15 = layer1
    const int wl   = w16 & 7;           // wave within layer, owns tiles {2wl, 2wl+1}
    const int c    = lane & 15;         // batch (D col / B n-col)
    const int quad = lane >> 4;
    const int b0   = (int)blockIdx.x * MB;

    const int rdB0 = hidx(c, quad * 8);        // B-frag k 0..31 (n = batch c)
    const int rdB1 = hidx(c, quad * 8 + 32);   // B-frag k 32..63

    // A-row this lane holds (per tile τ): unit 4τ + (c>>2), gate c&3
    const int gA = c & 3;
    const int uA = c >> 2;
    const float sgA = (gA == 2) ? (2.f * L2E) : (-L2E);

    // ---- per-wave register weights: 2 tiles ----
    float bias[2][4], wih0[2][4];
    f16x8 aW[2][4];       // [tile][kchunk]; L0 uses 0..1, L1 uses 0..3
    int   wrA[2];         // LDS write index for this lane's point, per tile

#pragma unroll
    for (int ti = 0; ti < 2; ++ti) {
        const int tau = 2 * wl + ti;
        const int rho = 64 * gA + 4 * tau + uA;    // global W row held as A[m=c]
        wrA[ti] = hidx(c, 4 * tau + quad);
        if (!gB) {
#pragma unroll
            for (int kb = 0; kb < 2; ++kb) {
                const float* p = W_hh0 + rho * 64 + kb * 32 + quad * 8;
#pragma unroll
                for (int q = 0; q < 8; ++q) aW[ti][kb][q] = (_Float16)(p[q] * sgA);
            }
#pragma unroll
            for (int r = 0; r < 4; ++r) {
                const float sg = (r == 2) ? (2.f * L2E) : (-L2E);
                const int row = 64 * r + 4 * tau + quad;   // D row: gate r, unit
                bias[ti][r] = sg * (b_ih0[row] + b_hh0[row]);
                wih0[ti][r] = sg * W_ih0[row];             // D == 1
            }
        } else {
#pragma unroll
            for (int kb = 0; kb < 4; ++kb) {
                const int kk = kb * 32 + quad * 8;
                const float* p = (kk < 64) ? (W_ih1 + rho * 64 + kk)
                                           : (W_hh1 + rho * 64 + kk - 64);
#pragma unroll
                for (int q = 0; q < 8; ++q) aW[ti][kb][q] = (_Float16)(p[q] * sgA);
            }
#pragma unroll
            for (int r = 0; r < 4; ++r) {
                const float sg = (r == 2) ? (2.f * L2E) : (-L2E);
                const int row = 64 * r + 4 * tau + quad;
                bias[ti][r] = sg * (b_ih1[row] + b_hh1[row]);
            }
        }
    }

    // zero-init h buffers + flags
    for (int i = tid; i < 16 * 64; i += 1024) {
        h0s[0][i] = (_Float16)0.f; h0s[1][i] = (_Float16)0.f;
        h1s[0][i] = (_Float16)0.f; h1s[1][i] = (_Float16)0.f;
    }
    if (tid < 8)  flagL0[tid] = -1;
    else if (tid < 16) flagL1[tid - 8] = -1;
    __syncthreads();          // one-time init barrier

    float cst[2] = {0.f, 0.f};
    const f32x4 zf4 = {0.f, 0.f, 0.f, 0.f};
    const int fidx = lane & 7;

    // dataflow poll: wait until min(flagL0) >= n0 && min(flagL1) >= n1
    auto poll = [&](int n0, int n1) {
        while (true) {
            const int a = __hip_atomic_load(&flagL0[fidx], __ATOMIC_ACQUIRE,
                                            __HIP_MEMORY_SCOPE_WORKGROUP);
            const int b = __hip_atomic_load(&flagL1[fidx], __ATOMIC_ACQUIRE,
                                            __HIP_MEMORY_SCOPE_WORKGROUP);
            if (__all((a >= n0) && (b >= n1))) break;
            __builtin_amdgcn_s_sleep(1);
        }
    };

    if (!gB) {
        // ================= layer0 waves: self-paced over t =================
        float xv = x[(b0 + c) * TSTEPS + 0];          // x(0), broadcast over quads
        for (int t = 0; t < TSTEPS; ++t) {
            // prefetch x(t+1) early; consumed next iteration
            const int tn = (t + 1 < TSTEPS) ? (t + 1) : (TSTEPS - 1);
            const float xnext = x[(b0 + c) * TSTEPS + tn];

            poll(t - 1, t - 2);
            const int pr = (t + 1) & 1, pw = t & 1;
            const f16x8 bh0 = *(const f16x8*)&h0s[pr][rdB0];
            const f16x8 bh1 = *(const f16x8*)&h0s[pr][rdB1];
            f32x4 acc[2];
#pragma unroll
            for (int ti = 0; ti < 2; ++ti) {
                f32x4 ci;
#pragma unroll
                for (int r = 0; r < 4; ++r)
                    ci[r] = __builtin_fmaf(xv, wih0[ti][r], bias[ti][r]);
                acc[ti] = __builtin_amdgcn_mfma_f32_16x16x32_f16(aW[ti][0], bh0, ci, 0, 0, 0);
                acc[ti] = __builtin_amdgcn_mfma_f32_16x16x32_f16(aW[ti][1], bh1, acc[ti], 0, 0, 0);
            }
#pragma unroll
            for (int ti = 0; ti < 2; ++ti) {
                const float hv = lstm_point(acc[ti][0], acc[ti][1],
                                            acc[ti][2], acc[ti][3], cst[ti]);
                h0s[pw][wrA[ti]] = (_Float16)hv;
            }
            // release: h0(t) slice visible, then publish
            __hip_atomic_store(&flagL0[wl], t, __ATOMIC_RELEASE,
                               __HIP_MEMORY_SCOPE_WORKGROUP);
            xv = xnext;
        }
    } else {
        // ================= layer1 waves: self-paced over s =================
        for (int s = 0; s < TSTEPS; ++s) {
            poll(s, s - 1);
            const int prh0 = s & 1, prh1 = (s + 1) & 1, pwh1 = s & 1;
            const f16x8 b00 = *(const f16x8*)&h0s[prh0][rdB0];
            const f16x8 b01 = *(const f16x8*)&h0s[prh0][rdB1];
            const f16x8 b10 = *(const f16x8*)&h1s[prh1][rdB0];
            const f16x8 b11 = *(const f16x8*)&h1s[prh1][rdB1];
            f32x4 acc[2];
#pragma unroll
            for (int ti = 0; ti < 2; ++ti) {
                f32x4 ci;
#pragma unroll
                for (int r = 0; r < 4; ++r) ci[r] = bias[ti][r];
                f32x4 aP = __builtin_amdgcn_mfma_f32_16x16x32_f16(aW[ti][0], b00, ci, 0, 0, 0);
                aP = __builtin_amdgcn_mfma_f32_16x16x32_f16(aW[ti][1], b01, aP, 0, 0, 0);
                f32x4 aQ = __builtin_amdgcn_mfma_f32_16x16x32_f16(aW[ti][2], b10, zf4, 0, 0, 0);
                aQ = __builtin_amdgcn_mfma_f32_16x16x32_f16(aW[ti][3], b11, aQ, 0, 0, 0);
                acc[ti] = aP + aQ;
            }
#pragma unroll
            for (int ti = 0; ti < 2; ++ti) {
                const float hv = lstm_point(acc[ti][0], acc[ti][1],
                                            acc[ti][2], acc[ti][3], cst[ti]);
                h1s[pwh1][wrA[ti]] = (_Float16)hv;
            }
            __hip_atomic_store(&flagL1[wl], s, __ATOMIC_RELEASE,
                               __HIP_MEMORY_SCOPE_WORKGROUP);
        }
    }

    __syncthreads();          // all waves done; h0(511), h1(511) in parity 1

    if (tid < 32) {
        const int which = tid >> 4, m = tid & 15;
        const _Float16* hb = which ? &h1s[1][0] : &h0s[1][0];
        float s = b_fc[0];
        for (int jj = 0; jj < 64; ++jj) s += (float)hb[hidx(m, jj)] * W_fc[jj];
        out[which * 1024 + b0 + m] = s;
    }
}

extern "C" void kernel_launch(void* const* d_in, const int* in_sizes, int n_in,
                              void* d_out, int out_size, void* d_ws, size_t ws_size,
                              hipStream_t stream) {
    (void)in_sizes; (void)n_in; (void)d_ws; (void)ws_size; (void)out_size;
    lstm2_kernel<<<64, 1024, 0, stream>>>(
        (const float*)d_in[0],
        (const float*)d_in[1], (const float*)d_in[2],
        (const float*)d_in[3], (const float*)d_in[4],
        (const float*)d_in[5], (const float*)d_in[6],
        (const float*)d_in[7], (const float*)d_in[8],
        (const float*)d_in[9], (const float*)d_in[10],
        (float*)d_out);
}

// Round 10
// 474.612 us; speedup vs baseline: 1.0103x; 1.0103x over previous
//
#include <hip/hip_runtime.h>

// 2-layer LSTM, B=1024 T=512 D=1 H=64. 64 blocks x 1024 threads (16 waves).
// R10 = R8 layout + R9 flag dataflow + DEPTH-8 h rings (decouples L0 from L1).
//   waves 0-7  = layer0, wave wl owns unit-tiles {2wl, 2wl+1}
//   waves 8-15 = layer1, same tiling.
// Rings: h0s[8][16x64], h1s[8][16x64]; step t uses slot t&7.
// L0@t polls:  flags[0..7] >= t-1 (RAW h0(t-1)),  flags[8..15] >= t-8
//   (WAR: h0(t) overwrites slot of h0(t-8), last read by L1@(t-8)).
// L1@s polls:  flags[0..7] >= s (RAW h0(s)),      flags[8..15] >= s-1
//   (RAW h1(s-1); h1 WAR cleared by ring>=3 within-group skew<=1).
// Deadlock-free: L1@s <- L0@s <- L1@(s-8) <- ... strictly decreasing.
// Operand-swapped MFMA (R8): A = pre-gathered W rows (4 units x 4 gates),
// B = h (k=unit, n=batch); lane (c,quad) gets all 4 gates of
// (batch=c, unit=4*tile+quad) -> no shuffles, 2 points/lane.

typedef _Float16 f16x8 __attribute__((ext_vector_type(8)));
typedef float f32x4 __attribute__((ext_vector_type(4)));

#define TSTEPS 512
#define MB 16
#define L2E 1.44269504088896340736f

__device__ __forceinline__ int hidx(int row, int j) {
    // swizzled index into a 16x64 half tile (16B-block XOR swizzle)
    return row * 64 + ((((j >> 3) ^ (row & 7)) << 3) | (j & 7));
}

__device__ __forceinline__ float lstm_point(float ai, float af, float ag, float ao,
                                            float& c) {
    // ai,af,ao pre-scaled by -log2e ; ag by +2log2e  (R2-R9 proven numerics)
    const float p  = __builtin_amdgcn_exp2f(ai);
    const float s_ = __builtin_amdgcn_exp2f(af);
    const float r_ = __builtin_amdgcn_exp2f(ag);
    const float v  = __builtin_amdgcn_exp2f(ao);
    const float f  = __builtin_amdgcn_rcpf(1.f + s_);
    const float ig = (r_ - 1.f) * __builtin_amdgcn_rcpf((1.f + p) * (1.f + r_));
    const float cc = __builtin_fmaf(f, c, ig);
    c = cc;
    const float w  = __builtin_amdgcn_exp2f(cc * (2.f * L2E));
    return (w - 1.f) * __builtin_amdgcn_rcpf((1.f + v) * (1.f + w));
}

__global__ __launch_bounds__(1024) void lstm2_kernel(
    const float* __restrict__ x,
    const float* __restrict__ W_ih0, const float* __restrict__ W_hh0,
    const float* __restrict__ b_ih0, const float* __restrict__ b_hh0,
    const float* __restrict__ W_ih1, const float* __restrict__ W_hh1,
    const float* __restrict__ b_ih1, const float* __restrict__ b_hh1,
    const float* __restrict__ W_fc,  const float* __restrict__ b_fc,
    float* __restrict__ out)
{
    __shared__ __align__(16) _Float16 h0s[8][16 * 64];   // 16 KB ring
    __shared__ __align__(16) _Float16 h1s[8][16 * 64];   // 16 KB ring
    __shared__ int flags[16];    // [0..7] = L0 waves, [8..15] = L1 waves

    const int tid  = (int)threadIdx.x;
    const int lane = tid & 63;
    const int w16  = tid >> 6;          // wave 0..15
    const bool gB  = (w16 >= 8);        // waves 8-15 = layer1
    const int wl   = w16 & 7;           // wave within layer
    const int c    = lane & 15;         // batch (B n-col / D col)
    const int quad = lane >> 4;
    const int b0   = (int)blockIdx.x * MB;

    const int rdB0 = hidx(c, quad * 8);        // B-frag k 0..31
    const int rdB1 = hidx(c, quad * 8 + 32);   // B-frag k 32..63

    // A-row per tile τ: unit 4τ + (c>>2), gate c&3
    const int gA = c & 3;
    const int uA = c >> 2;
    const float sgA = (gA == 2) ? (2.f * L2E) : (-L2E);

    float bias[2][4], wih0[2][4];
    f16x8 aW[2][4];       // [tile][kchunk]; L0 uses 0..1, L1 uses 0..3
    int   wrA[2];

#pragma unroll
    for (int ti = 0; ti < 2; ++ti) {
        const int tau = 2 * wl + ti;
        const int rho = 64 * gA + 4 * tau + uA;
        wrA[ti] = hidx(c, 4 * tau + quad);
        if (!gB) {
#pragma unroll
            for (int kb = 0; kb < 2; ++kb) {
                const float* p = W_hh0 + rho * 64 + kb * 32 + quad * 8;
#pragma unroll
                for (int q = 0; q < 8; ++q) aW[ti][kb][q] = (_Float16)(p[q] * sgA);
            }
#pragma unroll
            for (int r = 0; r < 4; ++r) {
                const float sg = (r == 2) ? (2.f * L2E) : (-L2E);
                const int row = 64 * r + 4 * tau + quad;
                bias[ti][r] = sg * (b_ih0[row] + b_hh0[row]);
                wih0[ti][r] = sg * W_ih0[row];             // D == 1
            }
        } else {
#pragma unroll
            for (int kb = 0; kb < 4; ++kb) {
                const int kk = kb * 32 + quad * 8;
                const float* p = (kk < 64) ? (W_ih1 + rho * 64 + kk)
                                           : (W_hh1 + rho * 64 + kk - 64);
#pragma unroll
                for (int q = 0; q < 8; ++q) aW[ti][kb][q] = (_Float16)(p[q] * sgA);
            }
#pragma unroll
            for (int r = 0; r < 4; ++r) {
                const float sg = (r == 2) ? (2.f * L2E) : (-L2E);
                const int row = 64 * r + 4 * tau + quad;
                bias[ti][r] = sg * (b_ih1[row] + b_hh1[row]);
            }
        }
    }

    // zero-init rings (slot 7 must be zero for t=0 reads; init all) + flags
    for (int i = tid; i < 8 * 16 * 64; i += 1024) {
        ((_Float16*)h0s)[i] = (_Float16)0.f;
        ((_Float16*)h1s)[i] = (_Float16)0.f;
    }
    if (tid < 16) flags[tid] = -1;
    __syncthreads();          // one-time init barrier

    float cst[2] = {0.f, 0.f};
    const f32x4 zf4 = {0.f, 0.f, 0.f, 0.f};
    const int fsel = lane & 15;

    // poll: wait flags[0..7] >= n0 && flags[8..15] >= n1
    auto poll = [&](int n0, int n1) {
        const int thr = (fsel < 8) ? n0 : n1;
        while (true) {
            const int f = __hip_atomic_load(&flags[fsel], __ATOMIC_RELAXED,
                                            __HIP_MEMORY_SCOPE_WORKGROUP);
            if (__all(f >= thr)) break;
            __builtin_amdgcn_s_sleep(1);
        }
        __builtin_amdgcn_fence(__ATOMIC_ACQUIRE, "workgroup");
    };
    auto publish = [&](int v) {
        __builtin_amdgcn_fence(__ATOMIC_RELEASE, "workgroup");
        if (lane == 0)
            __hip_atomic_store(&flags[w16], v, __ATOMIC_RELAXED,
                               __HIP_MEMORY_SCOPE_WORKGROUP);
    };

    if (!gB) {
        // ================= layer0 waves: self-paced over t =================
        float xv = x[(b0 + c) * TSTEPS + 0];
        for (int t = 0; t < TSTEPS; ++t) {
            const int tn = (t + 1 < TSTEPS) ? (t + 1) : (TSTEPS - 1);
            const float xnext = x[(b0 + c) * TSTEPS + tn];

            poll(t - 1, t - 8);
            const int pr = (t - 1) & 7, pw = t & 7;
            const f16x8 bh0 = *(const f16x8*)&h0s[pr][rdB0];
            const f16x8 bh1 = *(const f16x8*)&h0s[pr][rdB1];
            f32x4 acc[2];
#pragma unroll
            for (int ti = 0; ti < 2; ++ti) {
                f32x4 ci;
#pragma unroll
                for (int r = 0; r < 4; ++r)
                    ci[r] = __builtin_fmaf(xv, wih0[ti][r], bias[ti][r]);
                acc[ti] = __builtin_amdgcn_mfma_f32_16x16x32_f16(aW[ti][0], bh0, ci, 0, 0, 0);
                acc[ti] = __builtin_amdgcn_mfma_f32_16x16x32_f16(aW[ti][1], bh1, acc[ti], 0, 0, 0);
            }
#pragma unroll
            for (int ti = 0; ti < 2; ++ti) {
                const float hv = lstm_point(acc[ti][0], acc[ti][1],
                                            acc[ti][2], acc[ti][3], cst[ti]);
                h0s[pw][wrA[ti]] = (_Float16)hv;
            }
            publish(t);
            xv = xnext;
        }
    } else {
        // ================= layer1 waves: self-paced over s =================
        for (int s = 0; s < TSTEPS; ++s) {
            poll(s, s - 1);
            const int prh0 = s & 7, prh1 = (s - 1) & 7, pwh1 = s & 7;
            const f16x8 b00 = *(const f16x8*)&h0s[prh0][rdB0];
            const f16x8 b01 = *(const f16x8*)&h0s[prh0][rdB1];
            const f16x8 b10 = *(const f16x8*)&h1s[prh1][rdB0];
            const f16x8 b11 = *(const f16x8*)&h1s[prh1][rdB1];
            f32x4 acc[2];
#pragma unroll
            for (int ti = 0; ti < 2; ++ti) {
                f32x4 ci;
#pragma unroll
                for (int r = 0; r < 4; ++r) ci[r] = bias[ti][r];
                f32x4 aP = __builtin_amdgcn_mfma_f32_16x16x32_f16(aW[ti][0], b00, ci, 0, 0, 0);
                aP = __builtin_amdgcn_mfma_f32_16x16x32_f16(aW[ti][1], b01, aP, 0, 0, 0);
                f32x4 aQ = __builtin_amdgcn_mfma_f32_16x16x32_f16(aW[ti][2], b10, zf4, 0, 0, 0);
                aQ = __builtin_amdgcn_mfma_f32_16x16x32_f16(aW[ti][3], b11, aQ, 0, 0, 0);
                acc[ti] = aP + aQ;
            }
#pragma unroll
            for (int ti = 0; ti < 2; ++ti) {
                const float hv = lstm_point(acc[ti][0], acc[ti][1],
                                            acc[ti][2], acc[ti][3], cst[ti]);
                h1s[pwh1][wrA[ti]] = (_Float16)hv;
            }
            publish(s);
        }
    }

    __syncthreads();          // h0(511), h1(511) in slot 511&7 = 7

    if (tid < 32) {
        const int which = tid >> 4, m = tid & 15;
        const _Float16* hb = which ? &h1s[7][0] : &h0s[7][0];
        float s = b_fc[0];
        for (int jj = 0; jj < 64; ++jj) s += (float)hb[hidx(m, jj)] * W_fc[jj];
        out[which * 1024 + b0 + m] = s;
    }
}

extern "C" void kernel_launch(void* const* d_in, const int* in_sizes, int n_in,
                              void* d_out, int out_size, void* d_ws, size_t ws_size,
                              hipStream_t stream) {
    (void)in_sizes; (void)n_in; (void)d_ws; (void)ws_size; (void)out_size;
    lstm2_kernel<<<64, 1024, 0, stream>>>(
        (const float*)d_in[0],
        (const float*)d_in[1], (const float*)d_in[2],
        (const float*)d_in[3], (const float*)d_in[4],
        (const float*)d_in[5], (const float*)d_in[6],
        (const float*)d_in[7], (const float*)d_in[8],
        (const float*)d_in[9], (const float*)d_in[10],
        (float*)d_out);
}